// Round 1
// baseline (1322.880 us; speedup 1.0000x reference)
//
#include <hip/hip_runtime.h>

// MultiLoraLinear: y = x@W^T + bias + (x@A^T)@Bw^T (per-segment adapter, scale=1)
// M=16384 (8x2048), K=4096, N=4096, r=16.
// Strategy: bf16-cast + MFMA NT-GEMM (m97 structure), LoRA folded in as an
// extra K-tile (u = x@A^T padded to 32 cols; Bw padded to 32 cols).

typedef __attribute__((ext_vector_type(8))) short short8;
typedef __attribute__((ext_vector_type(4))) float f32x4;
typedef __attribute__((ext_vector_type(4))) unsigned short u16x4;
typedef unsigned short u16;

typedef __attribute__((address_space(1))) void as1_void;
typedef __attribute__((address_space(3))) void as3_void;

#define M_DIM 16384
#define N_DIM 4096
#define K_DIM 4096

__device__ __forceinline__ u16 f2bf(float f) {
  union { float f; unsigned u; } v; v.f = f;
  unsigned r = (v.u + 0x7FFFu + ((v.u >> 16) & 1u)) >> 16;  // RNE
  return (u16)r;
}
__device__ __forceinline__ float bf2f(u16 u) {
  union { unsigned u; float f; } v; v.u = ((unsigned)u) << 16;
  return v.f;
}
__device__ __forceinline__ void gload16(const void* g, void* lds) {
  // async global->LDS, 16B/lane; LDS dest = wave-uniform base + lane*16
  __builtin_amdgcn_global_load_lds((as1_void*)g, (as3_void*)lds, 16, 0, 0);
}
__device__ __forceinline__ int seg_of_batch(const int* starts, int b) {
  int seg = -1;
#pragma unroll
  for (int i = 0; i < 4; ++i) seg += (starts[i] <= b) ? 1 : 0;
  return seg;  // 0 = no LoRA; adapter = clamp(seg-1, 0, 2)
}

// ---------------- prep: fp32 -> bf16 casts + padded Bw ----------------
__global__ __launch_bounds__(256) void prep_kernel(
    const float* __restrict__ x, const float* __restrict__ wgt,
    const float* __restrict__ lA, const float* __restrict__ lB,
    u16* __restrict__ xbf, u16* __restrict__ wbf,
    u16* __restrict__ abf, u16* __restrict__ bw) {
  const long long NX4 = 16777216LL;  // 67108864/4
  const long long NW4 = 4194304LL;   // 16777216/4
  const long long NA4 = 49152LL;     // 196608/4
  const long long NB  = 12288LL;     // 3*4096 (a,n) rows of lora_B
  const long long total = NX4 + NW4 + NA4 + NB;
  const f32x4* x4 = (const f32x4*)x;
  const f32x4* w4 = (const f32x4*)wgt;
  const f32x4* a4 = (const f32x4*)lA;
  u16x4* xo = (u16x4*)xbf;
  u16x4* wo = (u16x4*)wbf;
  u16x4* ao = (u16x4*)abf;
  for (long long i = (long long)blockIdx.x * blockDim.x + threadIdx.x; i < total;
       i += (long long)gridDim.x * blockDim.x) {
    if (i < NX4) {
      f32x4 v = x4[i];
      u16x4 o = {f2bf(v.x), f2bf(v.y), f2bf(v.z), f2bf(v.w)};
      xo[i] = o;
    } else if (i < NX4 + NW4) {
      long long j = i - NX4;
      f32x4 v = w4[j];
      u16x4 o = {f2bf(v.x), f2bf(v.y), f2bf(v.z), f2bf(v.w)};
      wo[j] = o;
    } else if (i < NX4 + NW4 + NA4) {
      long long j = i - NX4 - NW4;
      f32x4 v = a4[j];
      u16x4 o = {f2bf(v.x), f2bf(v.y), f2bf(v.z), f2bf(v.w)};
      ao[j] = o;
    } else {
      long long p = i - NX4 - NW4 - NA4;  // flat (a*4096+n)
      const float* src = lB + p * 16;
      u16* dst = bw + p * 32;
#pragma unroll
      for (int j = 0; j < 16; ++j) dst[j] = f2bf(src[j]);
#pragma unroll
      for (int j = 16; j < 32; ++j) dst[j] = 0;
    }
  }
}

// ---------------- u = x @ A^T  -> bf16 [M][32], zero-padded ----------------
// block = 256 (4 waves); each wave owns 4 rows; 16 rows/block; grid = 1024
__global__ __launch_bounds__(256) void ucompute_kernel(
    const u16* __restrict__ xbf, const u16* __restrict__ abf,
    const int* __restrict__ starts, u16* __restrict__ u) {
  const int l = threadIdx.x & 63;
  const int w = threadIdx.x >> 6;
  const int mbase = blockIdx.x * 16 + w * 4;
  const int b = mbase >> 11;  // /2048
  const int seg = seg_of_batch(starts, b);
  const int use = seg > 0;
  int ad = seg - 1; ad = ad < 0 ? 0 : (ad > 2 ? 2 : ad);

  float acc[4][16];
#pragma unroll
  for (int row = 0; row < 4; ++row)
#pragma unroll
    for (int r = 0; r < 16; ++r) acc[row][r] = 0.f;

  if (use) {
    const u16* xr = xbf + (size_t)mbase * K_DIM + l * 8;
    const u16* ar = abf + (size_t)ad * (16 * K_DIM) + l * 8;
    for (int pass = 0; pass < 8; ++pass) {
      const int off = pass * 512;
      float xv[4][8];
#pragma unroll
      for (int row = 0; row < 4; ++row) {
        short8 xs = *(const short8*)(xr + (size_t)row * K_DIM + off);
#pragma unroll
        for (int j = 0; j < 8; ++j) xv[row][j] = bf2f((u16)xs[j]);
      }
#pragma unroll
      for (int r = 0; r < 16; ++r) {
        short8 av = *(const short8*)(ar + (size_t)r * K_DIM + off);
#pragma unroll
        for (int j = 0; j < 8; ++j) {
          float a = bf2f((u16)av[j]);
#pragma unroll
          for (int row = 0; row < 4; ++row) acc[row][r] += xv[row][j] * a;
        }
      }
    }
  }
#pragma unroll
  for (int row = 0; row < 4; ++row) {
    float myval = 0.f;
#pragma unroll
    for (int r = 0; r < 16; ++r) {
      float v = acc[row][r];
      v += __shfl_xor(v, 32);
      v += __shfl_xor(v, 16);
      v += __shfl_xor(v, 8);
      v += __shfl_xor(v, 4);
      v += __shfl_xor(v, 2);
      v += __shfl_xor(v, 1);
      if (l == r) myval = v;  // lane r keeps u[m][r]
    }
    if (l < 32) u[(size_t)(mbase + row) * 32 + l] = (l < 16) ? f2bf(myval) : (u16)0;
  }
}

// ---------------- main NT-GEMM, 128x128 tile, bf16 MFMA 16x16x32 ----------------
__device__ __forceinline__ void do_tile(const u16* ard, const u16* brd,
                                        f32x4 (&acc)[4][4]) {
  short8 af[4], bf_[4];
#pragma unroll
  for (int i = 0; i < 4; ++i) af[i] = *(const short8*)(ard + i * 512);
#pragma unroll
  for (int j = 0; j < 4; ++j) bf_[j] = *(const short8*)(brd + j * 512);
#pragma unroll
  for (int i = 0; i < 4; ++i)
#pragma unroll
    for (int j = 0; j < 4; ++j)
      acc[i][j] = __builtin_amdgcn_mfma_f32_16x16x32_bf16(af[i], bf_[j], acc[i][j], 0, 0, 0);
}

__global__ __launch_bounds__(256) void gemm_kernel(
    const u16* __restrict__ xbf, const u16* __restrict__ wbf,
    const float* __restrict__ bias, const u16* __restrict__ ubuf,
    const u16* __restrict__ bwpad, const int* __restrict__ starts,
    float* __restrict__ out) {
  __shared__ u16 As[128 * 32];
  __shared__ u16 Bs[128 * 32];

  const int tid = threadIdx.x;
  const int l = tid & 63;
  const int w = tid >> 6;
  const int m0 = blockIdx.y << 7;
  const int n0 = blockIdx.x << 7;

  const int b = m0 >> 11;
  const int seg = seg_of_batch(starts, b);
  int ad = seg - 1; ad = ad < 0 ? 0 : (ad > 2 ? 2 : ad);
  // (no-LoRA blocks: u rows are zero, so staged Bw contributes nothing)

  // staging: per wave two 1KB regions; lane covers row (l>>2), 16B chunk (l&3)
  const int srow = l >> 2;
  const int scolb = (l & 3) << 4;
  const int reg0 = w * 2;
  const int r0row = reg0 * 16 + srow;
  const int r1row = (reg0 + 1) * 16 + srow;

  const char* a0 = (const char*)(xbf + (size_t)(m0 + r0row) * K_DIM) + scolb;
  const char* a1 = (const char*)(xbf + (size_t)(m0 + r1row) * K_DIM) + scolb;
  const char* b0 = (const char*)(wbf + (size_t)(n0 + r0row) * K_DIM) + scolb;
  const char* b1 = (const char*)(wbf + (size_t)(n0 + r1row) * K_DIM) + scolb;

  u16* lda0 = As + reg0 * 512;       // wave-uniform LDS dests (1KB regions)
  u16* lda1 = As + (reg0 + 1) * 512;
  u16* ldb0 = Bs + reg0 * 512;
  u16* ldb1 = Bs + (reg0 + 1) * 512;

  // fragment read addrs: A[m=l&15][k=(l>>4)*8..+8] (same for B in NT layout)
  const int fm = l & 15;
  const int fk = (l >> 4) << 3;
  const int wr = w >> 1, wc = w & 1;
  const u16* ard = As + (size_t)(wr * 64 + fm) * 32 + fk;
  const u16* brd = Bs + (size_t)(wc * 64 + fm) * 32 + fk;

  f32x4 acc[4][4];
  const f32x4 z4 = {0.f, 0.f, 0.f, 0.f};
#pragma unroll
  for (int i = 0; i < 4; ++i)
#pragma unroll
    for (int j = 0; j < 4; ++j) acc[i][j] = z4;

  for (int kt = 0; kt < 128; ++kt) {
    const size_t off = (size_t)kt << 6;  // 32 bf16 = 64B along K
    gload16(a0 + off, lda0);
    gload16(a1 + off, lda1);
    gload16(b0 + off, ldb0);
    gload16(b1 + off, ldb1);
    __syncthreads();
    do_tile(ard, brd, acc);
    __syncthreads();
  }
  // LoRA K-tile: A-side = u[M][32], B-side = bwpad[ad][N][32]
  gload16((const char*)(ubuf + (size_t)(m0 + r0row) * 32) + scolb, lda0);
  gload16((const char*)(ubuf + (size_t)(m0 + r1row) * 32) + scolb, lda1);
  gload16((const char*)(bwpad + ((size_t)ad * N_DIM + n0 + r0row) * 32) + scolb, ldb0);
  gload16((const char*)(bwpad + ((size_t)ad * N_DIM + n0 + r1row) * 32) + scolb, ldb1);
  __syncthreads();
  do_tile(ard, brd, acc);

  // epilogue: C/D layout col=l&15, row=(l>>4)*4+reg
  float bv[4];
#pragma unroll
  for (int j = 0; j < 4; ++j) bv[j] = bias[n0 + wc * 64 + j * 16 + fm];
  const int q = l >> 4;
#pragma unroll
  for (int i = 0; i < 4; ++i) {
#pragma unroll
    for (int ii = 0; ii < 4; ++ii) {
      const int m = m0 + wr * 64 + i * 16 + q * 4 + ii;
      float* orow = out + (size_t)m * N_DIM + n0 + wc * 64 + fm;
#pragma unroll
      for (int j = 0; j < 4; ++j) orow[j * 16] = acc[i][j][ii] + bv[j];
    }
  }
}

// ---------------- fp32 fallback (only if ws_size < fast-path need) ----------------
__global__ __launch_bounds__(256) void u_f32_kernel(
    const float* __restrict__ x, const float* __restrict__ lA,
    const int* __restrict__ starts, float* __restrict__ u) {
  const int l = threadIdx.x & 63;
  const int w = threadIdx.x >> 6;
  const int m = blockIdx.x * 4 + w;
  const int b = m >> 11;
  const int seg = seg_of_batch(starts, b);
  const int use = seg > 0;
  int ad = seg - 1; ad = ad < 0 ? 0 : (ad > 2 ? 2 : ad);
  float acc[16];
#pragma unroll
  for (int r = 0; r < 16; ++r) acc[r] = 0.f;
  if (use) {
    const float* xr = x + (size_t)m * K_DIM + l * 4;
    const float* ar = lA + (size_t)ad * (16 * K_DIM) + l * 4;
    for (int pass = 0; pass < 16; ++pass) {
      const int off = pass * 256;
      f32x4 xv = *(const f32x4*)(xr + off);
#pragma unroll
      for (int r = 0; r < 16; ++r) {
        f32x4 av = *(const f32x4*)(ar + (size_t)r * K_DIM + off);
        acc[r] += xv.x * av.x + xv.y * av.y + xv.z * av.z + xv.w * av.w;
      }
    }
  }
  float myval = 0.f;
#pragma unroll
  for (int r = 0; r < 16; ++r) {
    float v = acc[r];
    v += __shfl_xor(v, 32);
    v += __shfl_xor(v, 16);
    v += __shfl_xor(v, 8);
    v += __shfl_xor(v, 4);
    v += __shfl_xor(v, 2);
    v += __shfl_xor(v, 1);
    if (l == r) myval = v;
  }
  if (l < 16) u[(size_t)m * 16 + l] = myval;
}

__global__ __launch_bounds__(256) void gemm_f32_fallback(
    const float* __restrict__ x, const float* __restrict__ wgt,
    const float* __restrict__ bias, const float* __restrict__ lB,
    const float* __restrict__ u, const int* __restrict__ starts,
    float* __restrict__ out) {
  __shared__ float xs[4096];
  const int m = blockIdx.y;
  const int n0 = blockIdx.x * 256;
  const int t = threadIdx.x;
  const f32x4* xr4 = (const f32x4*)(x + (size_t)m * K_DIM);
  f32x4* xs4 = (f32x4*)xs;
  for (int i = t; i < 1024; i += 256) xs4[i] = xr4[i];
  __syncthreads();
  const int b = m >> 11;
  const int seg = seg_of_batch(starts, b);
  const int use = seg > 0;
  int ad = seg - 1; ad = ad < 0 ? 0 : (ad > 2 ? 2 : ad);
  const int n = n0 + t;
  const f32x4* wr = (const f32x4*)(wgt + (size_t)n * K_DIM);
  float acc = 0.f;
  for (int kk = 0; kk < 1024; ++kk) {
    f32x4 wv = wr[kk];
    f32x4 xv = xs4[kk];
    acc += xv.x * wv.x + xv.y * wv.y + xv.z * wv.z + xv.w * wv.w;
  }
  acc += bias[n];
  if (use) {
    const float* Bn = lB + ((size_t)ad * N_DIM + n) * 16;
    const float* um = u + (size_t)m * 16;
    float lo = 0.f;
#pragma unroll
    for (int r = 0; r < 16; ++r) lo += um[r] * Bn[r];
    acc += lo;
  }
  out[(size_t)m * N_DIM + n] = acc;
}

extern "C" void kernel_launch(void* const* d_in, const int* in_sizes, int n_in,
                              void* d_out, int out_size, void* d_ws, size_t ws_size,
                              hipStream_t stream) {
  const float* x    = (const float*)d_in[0];
  const float* wgt  = (const float*)d_in[1];
  const float* bias = (const float*)d_in[2];
  const float* lA   = (const float*)d_in[3];
  const float* lB   = (const float*)d_in[4];
  const int* starts = (const int*)d_in[5];
  float* out = (float*)d_out;

  const size_t XBF_OFF = 0;                      // 134217728 B
  const size_t WBF_OFF = 134217728;              //  33554432 B
  const size_t ABF_OFF = 167772160;              //    393216 B
  const size_t BW_OFF  = 168165376;              //    786432 B
  const size_t U_OFF   = 168951808;              //   1048576 B
  const size_t WS_NEEDED = 170000384;

  if (ws_size >= WS_NEEDED) {
    u16* xbf = (u16*)((char*)d_ws + XBF_OFF);
    u16* wbf = (u16*)((char*)d_ws + WBF_OFF);
    u16* abf = (u16*)((char*)d_ws + ABF_OFF);
    u16* bw  = (u16*)((char*)d_ws + BW_OFF);
    u16* u   = (u16*)((char*)d_ws + U_OFF);
    prep_kernel<<<8192, 256, 0, stream>>>(x, wgt, lA, lB, xbf, wbf, abf, bw);
    ucompute_kernel<<<1024, 256, 0, stream>>>(xbf, abf, starts, u);
    gemm_kernel<<<dim3(32, 128), 256, 0, stream>>>(xbf, wbf, bias, u, bw, starts, out);
  } else {
    // fp32 fallback: needs only 1 MB of ws for u
    float* uf = (float*)d_ws;
    u_f32_kernel<<<4096, 256, 0, stream>>>(x, lA, starts, uf);
    gemm_f32_fallback<<<dim3(16, 16384), 256, 0, stream>>>(x, wgt, bias, lB, uf, starts, out);
  }
}